// Round 1
// baseline (1358.401 us; speedup 1.0000x reference)
//
#include <hip/hip_runtime.h>
#include <cstddef>
#include <cstdint>

#define D_MODEL 1024
#define D_STATE 8
#define D_INNER 1536
#define SEQ_L   2048
#define BATCH   4
#define MROWS   (BATCH * SEQ_L)   // 8192

// ---------------------------------------------------------------- LayerNorm
__global__ __launch_bounds__(256) void ln_kernel(
    const float* __restrict__ x, const float* __restrict__ g,
    const float* __restrict__ b, float* __restrict__ y)
{
  const int row = blockIdx.x;
  const int t = threadIdx.x;           // 256 threads, 4 floats each = 1024
  float4 v = reinterpret_cast<const float4*>(x + (size_t)row * D_MODEL)[t];
  float s  = v.x + v.y + v.z + v.w;
  float s2 = v.x * v.x + v.y * v.y + v.z * v.z + v.w * v.w;
  #pragma unroll
  for (int o = 32; o > 0; o >>= 1) {
    s  += __shfl_down(s, o);
    s2 += __shfl_down(s2, o);
  }
  __shared__ float ls[4], ls2[4];
  const int wid = t >> 6, lid = t & 63;
  if (lid == 0) { ls[wid] = s; ls2[wid] = s2; }
  __syncthreads();
  if (t == 0) {
    ls[0]  = ls[0] + ls[1] + ls[2] + ls[3];
    ls2[0] = ls2[0] + ls2[1] + ls2[2] + ls2[3];
  }
  __syncthreads();
  const float mean = ls[0] * (1.0f / D_MODEL);
  const float var  = ls2[0] * (1.0f / D_MODEL) - mean * mean;
  const float rstd = rsqrtf(var + 1e-5f);
  float4 gv = reinterpret_cast<const float4*>(g)[t];
  float4 bv = reinterpret_cast<const float4*>(b)[t];
  float4 o;
  o.x = (v.x - mean) * rstd * gv.x + bv.x;
  o.y = (v.y - mean) * rstd * gv.y + bv.y;
  o.z = (v.z - mean) * rstd * gv.z + bv.z;
  o.w = (v.w - mean) * rstd * gv.w + bv.w;
  reinterpret_cast<float4*>(y + (size_t)row * D_MODEL)[t] = o;
}

// ------------------------------------------------- fp32 NT GEMM, 128x128x16
// C[r][c] = sum_k A[r][k] * B[c][k], clipped to [-5,5].
// c < split -> out0[r*ld0 + c] ; else -> out1[r*ld1 + (c-split)]
#define BM 128
#define BN 128
#define BKK 16

__global__ __launch_bounds__(256) void gemm_nt_kernel(
    const float* __restrict__ A, const float* __restrict__ Bm,
    float* __restrict__ out0, float* __restrict__ out1,
    int K, int split, int ld0, int ld1)
{
  __shared__ float As[BKK][BM + 4];
  __shared__ float Bs[BKK][BN + 4];
  const int t  = threadIdx.x;
  const int tx = t & 15, ty = t >> 4;
  const int m0 = blockIdx.x * BM, n0 = blockIdx.y * BN;
  const int sr = t >> 1;          // 0..127 : tile row staged by this thread
  const int sc = (t & 1) * 8;     // 0 or 8 : k-offset staged by this thread
  const float* Ap = A  + (size_t)(m0 + sr) * K + sc;
  const float* Bp = Bm + (size_t)(n0 + sr) * K + sc;

  float acc[8][8];
  #pragma unroll
  for (int i = 0; i < 8; i++)
    #pragma unroll
    for (int j = 0; j < 8; j++) acc[i][j] = 0.0f;

  for (int kk = 0; kk < K; kk += BKK) {
    float4 a0 = *reinterpret_cast<const float4*>(Ap + kk);
    float4 a1 = *reinterpret_cast<const float4*>(Ap + kk + 4);
    float4 b0 = *reinterpret_cast<const float4*>(Bp + kk);
    float4 b1 = *reinterpret_cast<const float4*>(Bp + kk + 4);
    __syncthreads();   // previous iteration's reads done before overwrite
    As[sc + 0][sr] = a0.x; As[sc + 1][sr] = a0.y;
    As[sc + 2][sr] = a0.z; As[sc + 3][sr] = a0.w;
    As[sc + 4][sr] = a1.x; As[sc + 5][sr] = a1.y;
    As[sc + 6][sr] = a1.z; As[sc + 7][sr] = a1.w;
    Bs[sc + 0][sr] = b0.x; Bs[sc + 1][sr] = b0.y;
    Bs[sc + 2][sr] = b0.z; Bs[sc + 3][sr] = b0.w;
    Bs[sc + 4][sr] = b1.x; Bs[sc + 5][sr] = b1.y;
    Bs[sc + 6][sr] = b1.z; Bs[sc + 7][sr] = b1.w;
    __syncthreads();
    #pragma unroll
    for (int k = 0; k < BKK; k++) {
      float4 av0 = *reinterpret_cast<const float4*>(&As[k][ty * 8]);
      float4 av1 = *reinterpret_cast<const float4*>(&As[k][ty * 8 + 4]);
      float4 bv0 = *reinterpret_cast<const float4*>(&Bs[k][tx * 8]);
      float4 bv1 = *reinterpret_cast<const float4*>(&Bs[k][tx * 8 + 4]);
      float av[8] = {av0.x, av0.y, av0.z, av0.w, av1.x, av1.y, av1.z, av1.w};
      float bv[8] = {bv0.x, bv0.y, bv0.z, bv0.w, bv1.x, bv1.y, bv1.z, bv1.w};
      #pragma unroll
      for (int im = 0; im < 8; im++)
        #pragma unroll
        for (int in = 0; in < 8; in++)
          acc[im][in] = fmaf(av[im], bv[in], acc[im][in]);
    }
  }

  #pragma unroll
  for (int im = 0; im < 8; im++) {
    const int r = m0 + ty * 8 + im;
    #pragma unroll
    for (int in = 0; in < 8; in++) {
      const int c = n0 + tx * 8 + in;
      float v = fminf(fmaxf(acc[im][in], -5.0f), 5.0f);
      if (c < split) out0[(size_t)r * ld0 + c] = v;
      else           out1[(size_t)r * ld1 + (c - split)] = v;
    }
  }
}

// --------------------------------------------------------------- SSM scan
// One thread per (b, i) channel; 8 states in registers; sequential over t.
// Reads x_ssm and (raw, clipped) gate; writes prod = y * tanh(gate) IN PLACE
// over x_ssm. Register prefetch depth PF to keep HBM loads in flight.
#define PF 16
__global__ __launch_bounds__(256) void scan_kernel(
    float* __restrict__ xssm, const float* __restrict__ gate,
    const float* __restrict__ A_log, const float* __restrict__ Bv,
    const float* __restrict__ Cv)
{
  const int gid = blockIdx.x * 256 + threadIdx.x;   // 0..6143
  const int b = gid / D_INNER;
  const int i = gid % D_INNER;

  float dec[D_STATE], bb[D_STATE], cc[D_STATE], h[D_STATE];
  #pragma unroll
  for (int s = 0; s < D_STATE; s++) {
    float al = A_log[i * D_STATE + s];
    al = fminf(fmaxf(al, -5.0f), 0.0f);
    float a = -__expf(al);
    a = fminf(fmaxf(a, -2.0f), -0.01f);
    dec[s] = a * 0.9f;
    bb[s]  = Bv[i * D_STATE + s] * 0.1f;
    cc[s]  = Cv[i * D_STATE + s];
    h[s]   = 0.0f;
  }

  const size_t base = (size_t)b * SEQ_L * D_INNER + i;
  float xf[PF], gf[PF];
  #pragma unroll
  for (int j = 0; j < PF; j++) {
    xf[j] = xssm[base + (size_t)j * D_INNER];
    gf[j] = gate[base + (size_t)j * D_INNER];
  }

  for (int t0 = 0; t0 < SEQ_L; t0 += PF) {
    float xn[PF], gn[PF];
    if (t0 + PF < SEQ_L) {
      #pragma unroll
      for (int j = 0; j < PF; j++) {
        xn[j] = xssm[base + (size_t)(t0 + PF + j) * D_INNER];
        gn[j] = gate[base + (size_t)(t0 + PF + j) * D_INNER];
      }
    }
    #pragma unroll
    for (int j = 0; j < PF; j++) {
      const float x = xf[j];
      float y = 0.0f;
      #pragma unroll
      for (int s = 0; s < D_STATE; s++) {
        h[s] = fmaf(h[s], dec[s], x * bb[s]);
        h[s] = fminf(fmaxf(h[s], -5.0f), 5.0f);
        y = fmaf(h[s], cc[s], y);
      }
      y = fminf(fmaxf(y, -5.0f), 5.0f);
      const float e  = __expf(2.0f * gf[j]);
      const float th = __fdividef(e - 1.0f, e + 1.0f);
      xssm[base + (size_t)(t0 + j) * D_INNER] = y * th;
    }
    #pragma unroll
    for (int j = 0; j < PF; j++) { xf[j] = xn[j]; gf[j] = gn[j]; }
  }
}

// ---------------------------------------------------------------- launcher
extern "C" void kernel_launch(void* const* d_in, const int* in_sizes, int n_in,
                              void* d_out, int out_size, void* d_ws, size_t ws_size,
                              hipStream_t stream)
{
  const float* x        = (const float*)d_in[0];
  const float* W_in     = (const float*)d_in[1];
  const float* W_out    = (const float*)d_in[2];
  const float* A_log    = (const float*)d_in[3];
  const float* Bmat     = (const float*)d_in[4];
  const float* Cmat     = (const float*)d_in[5];
  const float* ln_in_g  = (const float*)d_in[6];
  const float* ln_in_b  = (const float*)d_in[7];
  const float* ln_out_g = (const float*)d_in[8];
  const float* ln_out_b = (const float*)d_in[9];
  float* out = (float*)d_out;

  // workspace layout (floats): xn[8192*1024] | xssm[8192*1536] | gate[8192*1536] | outp[8192*1024]
  float* xn   = (float*)d_ws;
  float* xssm = xn   + (size_t)MROWS * D_MODEL;
  float* gate = xssm + (size_t)MROWS * D_INNER;
  float* outp = gate + (size_t)MROWS * D_INNER;

  // 1) LayerNorm-in
  ln_kernel<<<MROWS, 256, 0, stream>>>(x, ln_in_g, ln_in_b, xn);

  // 2) x_proj = clip(xn @ W_in^T): split-store into xssm (c<1536) and gate
  {
    dim3 grid(MROWS / BM, (2 * D_INNER) / BN);   // 64 x 24
    gemm_nt_kernel<<<grid, 256, 0, stream>>>(xn, W_in, xssm, gate,
                                             D_MODEL, D_INNER, D_INNER, D_INNER);
  }

  // 3) sequential SSM scan; prod = y * tanh(gate) written in place over xssm
  scan_kernel<<<(BATCH * D_INNER) / 256, 256, 0, stream>>>(xssm, gate, A_log, Bmat, Cmat);

  // 4) out_pre = clip(prod @ W_out^T)
  {
    dim3 grid(MROWS / BM, D_MODEL / BN);          // 64 x 8
    gemm_nt_kernel<<<grid, 256, 0, stream>>>(xssm, W_out, outp, outp,
                                             D_INNER, D_MODEL, D_MODEL, D_MODEL);
  }

  // 5) LayerNorm-out -> d_out
  ln_kernel<<<MROWS, 256, 0, stream>>>(outp, ln_out_g, ln_out_b, out);
}

// Round 2
// 764.564 us; speedup vs baseline: 1.7767x; 1.7767x over previous
//
#include <hip/hip_runtime.h>
#include <cstddef>
#include <cstdint>

#define D_MODEL 1024
#define D_STATE 8
#define D_INNER 1536
#define SEQ_L   2048
#define BATCH   4
#define MROWS   (BATCH * SEQ_L)   // 8192

typedef __attribute__((ext_vector_type(8))) short short8;
typedef __attribute__((ext_vector_type(4))) float f32x4;
typedef unsigned int u32;
typedef unsigned short u16;

__device__ __forceinline__ u16 bf_hi(float x) {            // truncate fp32 -> bf16
  return (u16)(__float_as_uint(x) >> 16);
}
__device__ __forceinline__ float bf_f(u16 h) {
  return __uint_as_float(((u32)h) << 16);
}
__device__ __forceinline__ void gload16(const void* g, void* l) {
  __builtin_amdgcn_global_load_lds((const __attribute__((address_space(1))) u32*)g,
                                   (__attribute__((address_space(3))) u32*)l, 16, 0, 0);
}

// ---------------------------------------------------------------- LayerNorm
__global__ __launch_bounds__(256) void ln_kernel(
    const float* __restrict__ x, const float* __restrict__ g,
    const float* __restrict__ b, float* __restrict__ y)
{
  const int row = blockIdx.x;
  const int t = threadIdx.x;
  float4 v = reinterpret_cast<const float4*>(x + (size_t)row * D_MODEL)[t];
  float s  = v.x + v.y + v.z + v.w;
  float s2 = v.x * v.x + v.y * v.y + v.z * v.z + v.w * v.w;
  #pragma unroll
  for (int o = 32; o > 0; o >>= 1) {
    s  += __shfl_down(s, o);
    s2 += __shfl_down(s2, o);
  }
  __shared__ float ls[4], ls2[4];
  const int wid = t >> 6, lid = t & 63;
  if (lid == 0) { ls[wid] = s; ls2[wid] = s2; }
  __syncthreads();
  if (t == 0) {
    ls[0]  = ls[0] + ls[1] + ls[2] + ls[3];
    ls2[0] = ls2[0] + ls2[1] + ls2[2] + ls2[3];
  }
  __syncthreads();
  const float mean = ls[0] * (1.0f / D_MODEL);
  const float var  = ls2[0] * (1.0f / D_MODEL) - mean * mean;
  const float rstd = rsqrtf(var + 1e-5f);
  float4 gv = reinterpret_cast<const float4*>(g)[t];
  float4 bv = reinterpret_cast<const float4*>(b)[t];
  float4 o;
  o.x = (v.x - mean) * rstd * gv.x + bv.x;
  o.y = (v.y - mean) * rstd * gv.y + bv.y;
  o.z = (v.z - mean) * rstd * gv.z + bv.z;
  o.w = (v.w - mean) * rstd * gv.w + bv.w;
  reinterpret_cast<float4*>(y + (size_t)row * D_MODEL)[t] = o;
}

// ------------------------------------------------- weight split kernels
__global__ __launch_bounds__(256) void wsplit3_kernel(
    const float* __restrict__ W, u16* __restrict__ a0, u16* __restrict__ a1,
    u16* __restrict__ a2, int n)
{
  int i = blockIdx.x * 256 + threadIdx.x;
  if (i >= n) return;
  float x = W[i];
  u16 h0 = bf_hi(x); float r1 = x - bf_f(h0);
  u16 h1 = bf_hi(r1); float r2 = r1 - bf_f(h1);
  a0[i] = h0; a1[i] = h1; a2[i] = bf_hi(r2);
}

__global__ __launch_bounds__(256) void wsplit2_kernel(
    const float* __restrict__ W, u16* __restrict__ a0, u16* __restrict__ a1, int n)
{
  int i = blockIdx.x * 256 + threadIdx.x;
  if (i >= n) return;
  float x = W[i];
  u16 h0 = bf_hi(x); float r1 = x - bf_f(h0);
  a0[i] = h0; a1[i] = bf_hi(r1);
}

// ---------------------------------------------------------------- GEMM1
// out = clip(xn @ W_in^T). A: fp32 [8192][1024] converted in-kernel to 3-term
// bf16; B: 3-term pre-split bf16 [3072][1024]. 6 MFMA combos (ta+tb<=2).
// 128x128 tile, BK=32, 4 waves, each 4x4 of 16x16x32 fragments.
__global__ __launch_bounds__(256, 2) void gemm1_kernel(
    const float* __restrict__ A, const u16* __restrict__ B0,
    const u16* __restrict__ B1, const u16* __restrict__ B2,
    float* __restrict__ out0, float* __restrict__ out1)
{
  __shared__ u16 As[3][128 * 32];
  __shared__ u16 Bs[3][128 * 32];
  const int t = threadIdx.x;
  const int wave = t >> 6, lane = t & 63;
  const int wr = wave >> 1, wc = wave & 1;
  const int q = lane >> 4, m16 = lane & 15;
  const int m0 = blockIdx.x * 128, n0 = blockIdx.y * 128;

  const int ar = t >> 1, ak = (t & 1) * 16;        // A staging: row, k-offset
  const float* Ap = A + (size_t)(m0 + ar) * D_MODEL + ak;
  const int brow = wave * 32 + (lane >> 2);        // B staging rows
  const int bk = (lane & 3) * 8;
  const u16* Bsrc[3] = {B0, B1, B2};

  f32x4 acc[4][4];
  #pragma unroll
  for (int i = 0; i < 4; i++)
    #pragma unroll
    for (int j = 0; j < 4; j++) acc[i][j] = (f32x4)(0.0f);

  for (int kk = 0; kk < D_MODEL; kk += 32) {
    // load + convert A chunk in registers (overlaps with previous compute)
    float4 f[4];
    #pragma unroll
    for (int i = 0; i < 4; i++)
      f[i] = *reinterpret_cast<const float4*>(Ap + kk + i * 4);
    u16 u0[16], u1[16], u2[16];
    #pragma unroll
    for (int i = 0; i < 4; i++) {
      float e0 = f[i].x, e1 = f[i].y, e2 = f[i].z, e3 = f[i].w;
      float ee[4] = {e0, e1, e2, e3};
      #pragma unroll
      for (int j = 0; j < 4; j++) {
        float x = ee[j];
        u16 h0 = bf_hi(x); float r1 = x - bf_f(h0);
        u16 h1 = bf_hi(r1); float r2 = r1 - bf_f(h1);
        u0[i * 4 + j] = h0; u1[i * 4 + j] = h1; u2[i * 4 + j] = bf_hi(r2);
      }
    }
    __syncthreads();   // previous tile fully consumed
    // B: async global->LDS, 3 terms x 2 instrs (16 rows each) per wave
    #pragma unroll
    for (int term = 0; term < 3; term++) {
      #pragma unroll
      for (int j = 0; j < 2; j++) {
        const u16* gp = Bsrc[term] + (size_t)(n0 + brow + j * 16) * D_MODEL + kk + bk;
        gload16(gp, &Bs[term][(wave * 32 + j * 16) * 32]);
      }
    }
    // A: write converted terms to LDS (2 x b128 per term)
    #pragma unroll
    for (int term = 0; term < 3; term++) {
      const u16* uu = (term == 0) ? u0 : (term == 1) ? u1 : u2;
      short8 s;
      #pragma unroll
      for (int j = 0; j < 8; j++) s[j] = (short)uu[j];
      *reinterpret_cast<short8*>(&As[term][ar * 32 + ak]) = s;
      #pragma unroll
      for (int j = 0; j < 8; j++) s[j] = (short)uu[8 + j];
      *reinterpret_cast<short8*>(&As[term][ar * 32 + ak + 8]) = s;
    }
    __syncthreads();   // all staging (incl. global_load_lds) drained
    #pragma unroll
    for (int ta = 0; ta < 3; ta++) {
      short8 af[4];
      #pragma unroll
      for (int mt = 0; mt < 4; mt++)
        af[mt] = *reinterpret_cast<const short8*>(
            &As[ta][(wr * 64 + mt * 16 + m16) * 32 + q * 8]);
      #pragma unroll
      for (int tb = 0; tb < 3 - ta; tb++) {
        short8 bfr[4];
        #pragma unroll
        for (int nt = 0; nt < 4; nt++)
          bfr[nt] = *reinterpret_cast<const short8*>(
              &Bs[tb][(wc * 64 + nt * 16 + m16) * 32 + q * 8]);
        #pragma unroll
        for (int mt = 0; mt < 4; mt++)
          #pragma unroll
          for (int nt = 0; nt < 4; nt++)
            acc[mt][nt] = __builtin_amdgcn_mfma_f32_16x16x32_bf16(
                af[mt], bfr[nt], acc[mt][nt], 0, 0, 0);
      }
    }
  }
  // epilogue: C/D layout col=lane&15, row=(lane>>4)*4+reg  [m89/m91 verified]
  #pragma unroll
  for (int mt = 0; mt < 4; mt++) {
    #pragma unroll
    for (int nt = 0; nt < 4; nt++) {
      const int col = n0 + wc * 64 + nt * 16 + m16;
      #pragma unroll
      for (int r = 0; r < 4; r++) {
        const int row = m0 + wr * 64 + mt * 16 + q * 4 + r;
        float v = fminf(fmaxf(acc[mt][nt][r], -5.0f), 5.0f);
        if (col < D_INNER) out0[(size_t)row * D_INNER + col] = v;
        else               out1[(size_t)row * D_INNER + (col - D_INNER)] = v;
      }
    }
  }
}

// ---------------------------------------------------------------- GEMM2
// out = clip(prod @ W_out^T). A: 2-term bf16 [8192][1536]; B: 2-term
// [1024][1536]. 3 MFMA combos. All staging via global_load_lds.
__global__ __launch_bounds__(256, 2) void gemm2_kernel(
    const u16* __restrict__ P0, const u16* __restrict__ P1,
    const u16* __restrict__ V0, const u16* __restrict__ V1,
    float* __restrict__ out)
{
  __shared__ u16 As[2][128 * 32];
  __shared__ u16 Bs[2][128 * 32];
  const int t = threadIdx.x;
  const int wave = t >> 6, lane = t & 63;
  const int wr = wave >> 1, wc = wave & 1;
  const int q = lane >> 4, m16 = lane & 15;
  const int m0 = blockIdx.x * 128, n0 = blockIdx.y * 128;
  const int srow = wave * 32 + (lane >> 2);
  const int sk = (lane & 3) * 8;
  const u16* Asrc[2] = {P0, P1};
  const u16* Bsrc[2] = {V0, V1};

  f32x4 acc[4][4];
  #pragma unroll
  for (int i = 0; i < 4; i++)
    #pragma unroll
    for (int j = 0; j < 4; j++) acc[i][j] = (f32x4)(0.0f);

  for (int kk = 0; kk < D_INNER; kk += 32) {
    __syncthreads();
    #pragma unroll
    for (int term = 0; term < 2; term++) {
      #pragma unroll
      for (int j = 0; j < 2; j++) {
        const u16* ga = Asrc[term] + (size_t)(m0 + srow + j * 16) * D_INNER + kk + sk;
        gload16(ga, &As[term][(wave * 32 + j * 16) * 32]);
        const u16* gb = Bsrc[term] + (size_t)(n0 + srow + j * 16) * D_INNER + kk + sk;
        gload16(gb, &Bs[term][(wave * 32 + j * 16) * 32]);
      }
    }
    __syncthreads();
    #pragma unroll
    for (int ta = 0; ta < 2; ta++) {
      short8 af[4];
      #pragma unroll
      for (int mt = 0; mt < 4; mt++)
        af[mt] = *reinterpret_cast<const short8*>(
            &As[ta][(wr * 64 + mt * 16 + m16) * 32 + q * 8]);
      #pragma unroll
      for (int tb = 0; tb < 2 - ta; tb++) {
        short8 bfr[4];
        #pragma unroll
        for (int nt = 0; nt < 4; nt++)
          bfr[nt] = *reinterpret_cast<const short8*>(
              &Bs[tb][(wc * 64 + nt * 16 + m16) * 32 + q * 8]);
        #pragma unroll
        for (int mt = 0; mt < 4; mt++)
          #pragma unroll
          for (int nt = 0; nt < 4; nt++)
            acc[mt][nt] = __builtin_amdgcn_mfma_f32_16x16x32_bf16(
                af[mt], bfr[nt], acc[mt][nt], 0, 0, 0);
      }
    }
  }
  #pragma unroll
  for (int mt = 0; mt < 4; mt++) {
    #pragma unroll
    for (int nt = 0; nt < 4; nt++) {
      const int col = n0 + wc * 64 + nt * 16 + m16;
      #pragma unroll
      for (int r = 0; r < 4; r++) {
        const int row = m0 + wr * 64 + mt * 16 + q * 4 + r;
        float v = fminf(fmaxf(acc[mt][nt][r], -5.0f), 5.0f);
        out[(size_t)row * D_MODEL + col] = v;
      }
    }
  }
}

// --------------------------------------------------------------- SSM scan
// One thread per (b,i) channel; writes prod = y*tanh(gate) as 2-term bf16.
#define PF 16
__global__ __launch_bounds__(256) void scan_kernel(
    const float* __restrict__ xssm, const float* __restrict__ gate,
    const float* __restrict__ A_log, const float* __restrict__ Bv,
    const float* __restrict__ Cv, u16* __restrict__ P0, u16* __restrict__ P1)
{
  const int gid = blockIdx.x * 256 + threadIdx.x;   // 0..6143
  const int b = gid / D_INNER;
  const int i = gid % D_INNER;

  float dec[D_STATE], bb[D_STATE], cc[D_STATE], h[D_STATE];
  #pragma unroll
  for (int s = 0; s < D_STATE; s++) {
    float al = A_log[i * D_STATE + s];
    al = fminf(fmaxf(al, -5.0f), 0.0f);
    float a = -__expf(al);
    a = fminf(fmaxf(a, -2.0f), -0.01f);
    dec[s] = a * 0.9f;
    bb[s]  = Bv[i * D_STATE + s] * 0.1f;
    cc[s]  = Cv[i * D_STATE + s];
    h[s]   = 0.0f;
  }

  const size_t base = (size_t)b * SEQ_L * D_INNER + i;
  float xf[PF], gf[PF];
  #pragma unroll
  for (int j = 0; j < PF; j++) {
    xf[j] = xssm[base + (size_t)j * D_INNER];
    gf[j] = gate[base + (size_t)j * D_INNER];
  }

  for (int t0 = 0; t0 < SEQ_L; t0 += PF) {
    float xn[PF], gn[PF];
    if (t0 + PF < SEQ_L) {
      #pragma unroll
      for (int j = 0; j < PF; j++) {
        xn[j] = xssm[base + (size_t)(t0 + PF + j) * D_INNER];
        gn[j] = gate[base + (size_t)(t0 + PF + j) * D_INNER];
      }
    }
    #pragma unroll
    for (int j = 0; j < PF; j++) {
      const float x = xf[j];
      float y = 0.0f;
      #pragma unroll
      for (int s = 0; s < D_STATE; s++) {
        h[s] = fmaf(h[s], dec[s], x * bb[s]);
        h[s] = fminf(fmaxf(h[s], -5.0f), 5.0f);
        y = fmaf(h[s], cc[s], y);
      }
      y = fminf(fmaxf(y, -5.0f), 5.0f);
      const float e  = __expf(2.0f * gf[j]);
      const float th = __fdividef(e - 1.0f, e + 1.0f);
      const float p = y * th;
      const u16 h0 = bf_hi(p);
      const u16 h1 = bf_hi(p - bf_f(h0));
      P0[base + (size_t)(t0 + j) * D_INNER] = h0;
      P1[base + (size_t)(t0 + j) * D_INNER] = h1;
    }
    #pragma unroll
    for (int j = 0; j < PF; j++) { xf[j] = xn[j]; gf[j] = gn[j]; }
  }
}

// ---------------------------------------------------------------- launcher
extern "C" void kernel_launch(void* const* d_in, const int* in_sizes, int n_in,
                              void* d_out, int out_size, void* d_ws, size_t ws_size,
                              hipStream_t stream)
{
  const float* x        = (const float*)d_in[0];
  const float* W_in     = (const float*)d_in[1];
  const float* W_out    = (const float*)d_in[2];
  const float* A_log    = (const float*)d_in[3];
  const float* Bmat     = (const float*)d_in[4];
  const float* Cmat     = (const float*)d_in[5];
  const float* ln_in_g  = (const float*)d_in[6];
  const float* ln_in_b  = (const float*)d_in[7];
  const float* ln_out_g = (const float*)d_in[8];
  const float* ln_out_b = (const float*)d_in[9];
  float* out = (float*)d_out;

  // workspace layout (bytes):
  // [xssm 50331648][gate 50331648][xn 33554432][B0,B1,B2 3x6291456][V0,V1 2x3145728]
  // prod P0/P1 (2x25165824) overlays xn+Win region (dead after gemm1);
  // outp (33554432) overlays xssm (dead after scan). Total 159,383,552 B.
  char* ws = (char*)d_ws;
  float* xssm = (float*)(ws);
  float* gate = (float*)(ws + 50331648);
  float* xn   = (float*)(ws + 100663296);
  u16* B0 = (u16*)(ws + 134217728);
  u16* B1 = (u16*)(ws + 140509184);
  u16* B2 = (u16*)(ws + 146800640);
  u16* V0 = (u16*)(ws + 153092096);
  u16* V1 = (u16*)(ws + 156237824);
  u16* P0 = (u16*)xn;
  u16* P1 = P0 + (size_t)MROWS * D_INNER;
  float* outp = xssm;

  // 0) split weights into bf16 terms
  wsplit3_kernel<<<(2 * D_INNER * D_MODEL + 255) / 256, 256, 0, stream>>>(
      W_in, B0, B1, B2, 2 * D_INNER * D_MODEL);
  wsplit2_kernel<<<(D_MODEL * D_INNER + 255) / 256, 256, 0, stream>>>(
      W_out, V0, V1, D_MODEL * D_INNER);

  // 1) LayerNorm-in
  ln_kernel<<<MROWS, 256, 0, stream>>>(x, ln_in_g, ln_in_b, xn);

  // 2) x_proj = clip(xn @ W_in^T) via 6-MFMA 3-term split
  {
    dim3 grid(MROWS / 128, (2 * D_INNER) / 128);   // 64 x 24
    gemm1_kernel<<<grid, 256, 0, stream>>>(xn, B0, B1, B2, xssm, gate);
  }

  // 3) sequential SSM scan -> prod as 2-term bf16 (overlays dead xn/Win)
  scan_kernel<<<(BATCH * D_INNER) / 256, 256, 0, stream>>>(
      xssm, gate, A_log, Bmat, Cmat, P0, P1);

  // 4) out_pre = clip(prod @ W_out^T) via 3-MFMA 2-term split
  {
    dim3 grid(MROWS / 128, D_MODEL / 128);          // 64 x 8
    gemm2_kernel<<<grid, 256, 0, stream>>>(P0, P1, V0, V1, outp);
  }

  // 5) LayerNorm-out -> d_out
  ln_kernel<<<MROWS, 256, 0, stream>>>(outp, ln_out_g, ln_out_b, out);
}

// Round 3
// 495.978 us; speedup vs baseline: 2.7388x; 1.5415x over previous
//
#include <hip/hip_runtime.h>
#include <cstddef>
#include <cstdint>

#define D_MODEL 1024
#define D_STATE 8
#define D_INNER 1536
#define SEQ_L   2048
#define BATCH   4
#define MROWS   (BATCH * SEQ_L)   // 8192

// chunked scan: 16 chunks of 128, warmup 128 (|decay|<=0.55 -> err ~1e-32)
#define SCAN_CL 128
#define SCAN_W  128
#define SCAN_C  (SEQ_L / SCAN_CL)   // 16

typedef __attribute__((ext_vector_type(8))) short short8;
typedef __attribute__((ext_vector_type(4))) float f32x4;
typedef unsigned int u32;
typedef unsigned short u16;

__device__ __forceinline__ u16 bf_hi(float x) {            // truncate fp32 -> bf16
  return (u16)(__float_as_uint(x) >> 16);
}
__device__ __forceinline__ float bf_f(u16 h) {
  return __uint_as_float(((u32)h) << 16);
}
__device__ __forceinline__ void gload16(const void* g, void* l) {
  __builtin_amdgcn_global_load_lds((const __attribute__((address_space(1))) u32*)g,
                                   (__attribute__((address_space(3))) u32*)l, 16, 0, 0);
}

// ---------------------------------------------------------------- LayerNorm
__global__ __launch_bounds__(256) void ln_kernel(
    const float* __restrict__ x, const float* __restrict__ g,
    const float* __restrict__ b, float* __restrict__ y)
{
  const int row = blockIdx.x;
  const int t = threadIdx.x;
  float4 v = reinterpret_cast<const float4*>(x + (size_t)row * D_MODEL)[t];
  float s  = v.x + v.y + v.z + v.w;
  float s2 = v.x * v.x + v.y * v.y + v.z * v.z + v.w * v.w;
  #pragma unroll
  for (int o = 32; o > 0; o >>= 1) {
    s  += __shfl_down(s, o);
    s2 += __shfl_down(s2, o);
  }
  __shared__ float ls[4], ls2[4];
  const int wid = t >> 6, lid = t & 63;
  if (lid == 0) { ls[wid] = s; ls2[wid] = s2; }
  __syncthreads();
  if (t == 0) {
    ls[0]  = ls[0] + ls[1] + ls[2] + ls[3];
    ls2[0] = ls2[0] + ls2[1] + ls2[2] + ls2[3];
  }
  __syncthreads();
  const float mean = ls[0] * (1.0f / D_MODEL);
  const float var  = ls2[0] * (1.0f / D_MODEL) - mean * mean;
  const float rstd = rsqrtf(var + 1e-5f);
  float4 gv = reinterpret_cast<const float4*>(g)[t];
  float4 bv = reinterpret_cast<const float4*>(b)[t];
  float4 o;
  o.x = (v.x - mean) * rstd * gv.x + bv.x;
  o.y = (v.y - mean) * rstd * gv.y + bv.y;
  o.z = (v.z - mean) * rstd * gv.z + bv.z;
  o.w = (v.w - mean) * rstd * gv.w + bv.w;
  reinterpret_cast<float4*>(y + (size_t)row * D_MODEL)[t] = o;
}

// ------------------------------------------------- weight split kernels
__global__ __launch_bounds__(256) void wsplit3_kernel(
    const float* __restrict__ W, u16* __restrict__ a0, u16* __restrict__ a1,
    u16* __restrict__ a2, int n)
{
  int i = blockIdx.x * 256 + threadIdx.x;
  if (i >= n) return;
  float x = W[i];
  u16 h0 = bf_hi(x); float r1 = x - bf_f(h0);
  u16 h1 = bf_hi(r1); float r2 = r1 - bf_f(h1);
  a0[i] = h0; a1[i] = h1; a2[i] = bf_hi(r2);
}

__global__ __launch_bounds__(256) void wsplit2_kernel(
    const float* __restrict__ W, u16* __restrict__ a0, u16* __restrict__ a1, int n)
{
  int i = blockIdx.x * 256 + threadIdx.x;
  if (i >= n) return;
  float x = W[i];
  u16 h0 = bf_hi(x); float r1 = x - bf_f(h0);
  a0[i] = h0; a1[i] = bf_hi(r1);
}

// ---------------------------------------------------------------- GEMM1
// out = clip(xn @ W_in^T). A: fp32 [8192][1024] converted in-kernel to 3-term
// bf16; B: 3-term pre-split bf16 [3072][1024]. 6 MFMA combos (ta+tb<=2).
__global__ __launch_bounds__(256, 2) void gemm1_kernel(
    const float* __restrict__ A, const u16* __restrict__ B0,
    const u16* __restrict__ B1, const u16* __restrict__ B2,
    float* __restrict__ out0, float* __restrict__ out1)
{
  __shared__ u16 As[3][128 * 32];
  __shared__ u16 Bs[3][128 * 32];
  const int t = threadIdx.x;
  const int wave = t >> 6, lane = t & 63;
  const int wr = wave >> 1, wc = wave & 1;
  const int q = lane >> 4, m16 = lane & 15;
  const int m0 = blockIdx.x * 128, n0 = blockIdx.y * 128;

  const int ar = t >> 1, ak = (t & 1) * 16;
  const float* Ap = A + (size_t)(m0 + ar) * D_MODEL + ak;
  const int brow = wave * 32 + (lane >> 2);
  const int bk = (lane & 3) * 8;
  const u16* Bsrc[3] = {B0, B1, B2};

  f32x4 acc[4][4];
  #pragma unroll
  for (int i = 0; i < 4; i++)
    #pragma unroll
    for (int j = 0; j < 4; j++) acc[i][j] = (f32x4)(0.0f);

  for (int kk = 0; kk < D_MODEL; kk += 32) {
    float4 f[4];
    #pragma unroll
    for (int i = 0; i < 4; i++)
      f[i] = *reinterpret_cast<const float4*>(Ap + kk + i * 4);
    u16 u0[16], u1[16], u2[16];
    #pragma unroll
    for (int i = 0; i < 4; i++) {
      float ee[4] = {f[i].x, f[i].y, f[i].z, f[i].w};
      #pragma unroll
      for (int j = 0; j < 4; j++) {
        float x = ee[j];
        u16 h0 = bf_hi(x); float r1 = x - bf_f(h0);
        u16 h1 = bf_hi(r1); float r2 = r1 - bf_f(h1);
        u0[i * 4 + j] = h0; u1[i * 4 + j] = h1; u2[i * 4 + j] = bf_hi(r2);
      }
    }
    __syncthreads();
    #pragma unroll
    for (int term = 0; term < 3; term++) {
      #pragma unroll
      for (int j = 0; j < 2; j++) {
        const u16* gp = Bsrc[term] + (size_t)(n0 + brow + j * 16) * D_MODEL + kk + bk;
        gload16(gp, &Bs[term][(wave * 32 + j * 16) * 32]);
      }
    }
    #pragma unroll
    for (int term = 0; term < 3; term++) {
      const u16* uu = (term == 0) ? u0 : (term == 1) ? u1 : u2;
      short8 s;
      #pragma unroll
      for (int j = 0; j < 8; j++) s[j] = (short)uu[j];
      *reinterpret_cast<short8*>(&As[term][ar * 32 + ak]) = s;
      #pragma unroll
      for (int j = 0; j < 8; j++) s[j] = (short)uu[8 + j];
      *reinterpret_cast<short8*>(&As[term][ar * 32 + ak + 8]) = s;
    }
    __syncthreads();
    #pragma unroll
    for (int ta = 0; ta < 3; ta++) {
      short8 af[4];
      #pragma unroll
      for (int mt = 0; mt < 4; mt++)
        af[mt] = *reinterpret_cast<const short8*>(
            &As[ta][(wr * 64 + mt * 16 + m16) * 32 + q * 8]);
      #pragma unroll
      for (int tb = 0; tb < 3 - ta; tb++) {
        short8 bfr[4];
        #pragma unroll
        for (int nt = 0; nt < 4; nt++)
          bfr[nt] = *reinterpret_cast<const short8*>(
              &Bs[tb][(wc * 64 + nt * 16 + m16) * 32 + q * 8]);
        #pragma unroll
        for (int mt = 0; mt < 4; mt++)
          #pragma unroll
          for (int nt = 0; nt < 4; nt++)
            acc[mt][nt] = __builtin_amdgcn_mfma_f32_16x16x32_bf16(
                af[mt], bfr[nt], acc[mt][nt], 0, 0, 0);
      }
    }
  }
  #pragma unroll
  for (int mt = 0; mt < 4; mt++) {
    #pragma unroll
    for (int nt = 0; nt < 4; nt++) {
      const int col = n0 + wc * 64 + nt * 16 + m16;
      #pragma unroll
      for (int r = 0; r < 4; r++) {
        const int row = m0 + wr * 64 + mt * 16 + q * 4 + r;
        float v = fminf(fmaxf(acc[mt][nt][r], -5.0f), 5.0f);
        if (col < D_INNER) out0[(size_t)row * D_INNER + col] = v;
        else               out1[(size_t)row * D_INNER + (col - D_INNER)] = v;
      }
    }
  }
}

// ---------------------------------------------------------------- GEMM2
__global__ __launch_bounds__(256, 2) void gemm2_kernel(
    const u16* __restrict__ P0, const u16* __restrict__ P1,
    const u16* __restrict__ V0, const u16* __restrict__ V1,
    float* __restrict__ out)
{
  __shared__ u16 As[2][128 * 32];
  __shared__ u16 Bs[2][128 * 32];
  const int t = threadIdx.x;
  const int wave = t >> 6, lane = t & 63;
  const int wr = wave >> 1, wc = wave & 1;
  const int q = lane >> 4, m16 = lane & 15;
  const int m0 = blockIdx.x * 128, n0 = blockIdx.y * 128;
  const int srow = wave * 32 + (lane >> 2);
  const int sk = (lane & 3) * 8;
  const u16* Asrc[2] = {P0, P1};
  const u16* Bsrc[2] = {V0, V1};

  f32x4 acc[4][4];
  #pragma unroll
  for (int i = 0; i < 4; i++)
    #pragma unroll
    for (int j = 0; j < 4; j++) acc[i][j] = (f32x4)(0.0f);

  for (int kk = 0; kk < D_INNER; kk += 32) {
    __syncthreads();
    #pragma unroll
    for (int term = 0; term < 2; term++) {
      #pragma unroll
      for (int j = 0; j < 2; j++) {
        const u16* ga = Asrc[term] + (size_t)(m0 + srow + j * 16) * D_INNER + kk + sk;
        gload16(ga, &As[term][(wave * 32 + j * 16) * 32]);
        const u16* gb = Bsrc[term] + (size_t)(n0 + srow + j * 16) * D_INNER + kk + sk;
        gload16(gb, &Bs[term][(wave * 32 + j * 16) * 32]);
      }
    }
    __syncthreads();
    #pragma unroll
    for (int ta = 0; ta < 2; ta++) {
      short8 af[4];
      #pragma unroll
      for (int mt = 0; mt < 4; mt++)
        af[mt] = *reinterpret_cast<const short8*>(
            &As[ta][(wr * 64 + mt * 16 + m16) * 32 + q * 8]);
      #pragma unroll
      for (int tb = 0; tb < 2 - ta; tb++) {
        short8 bfr[4];
        #pragma unroll
        for (int nt = 0; nt < 4; nt++)
          bfr[nt] = *reinterpret_cast<const short8*>(
              &Bs[tb][(wc * 64 + nt * 16 + m16) * 32 + q * 8]);
        #pragma unroll
        for (int mt = 0; mt < 4; mt++)
          #pragma unroll
          for (int nt = 0; nt < 4; nt++)
            acc[mt][nt] = __builtin_amdgcn_mfma_f32_16x16x32_bf16(
                af[mt], bfr[nt], acc[mt][nt], 0, 0, 0);
      }
    }
  }
  #pragma unroll
  for (int mt = 0; mt < 4; mt++) {
    #pragma unroll
    for (int nt = 0; nt < 4; nt++) {
      const int col = n0 + wc * 64 + nt * 16 + m16;
      #pragma unroll
      for (int r = 0; r < 4; r++) {
        const int row = m0 + wr * 64 + mt * 16 + q * 4 + r;
        float v = fminf(fmaxf(acc[mt][nt][r], -5.0f), 5.0f);
        out[(size_t)row * D_MODEL + col] = v;
      }
    }
  }
}

// --------------------------------------------------------------- SSM scan
// Chunked: one thread per (chunk, b, i). Each chunk of SCAN_CL steps starts
// from h=0 at SCAN_W steps before its window; clip map is a contraction
// (|decay| <= ~0.55 for this data) so warmup error <= 10*0.55^128 ~ 1e-32.
// Chunk 0 starts exactly at t=0 with h=0 (no warmup, exact).
__global__ __launch_bounds__(256) void scan_kernel(
    const float* __restrict__ xssm, const float* __restrict__ gate,
    const float* __restrict__ A_log, const float* __restrict__ Bv,
    const float* __restrict__ Cv, u16* __restrict__ P0, u16* __restrict__ P1)
{
  const int gid = blockIdx.x * 256 + threadIdx.x;       // 0 .. 98303
  const int chunk = gid / (BATCH * D_INNER);            // 0..15
  const int rem = gid - chunk * (BATCH * D_INNER);
  const int b = rem / D_INNER;
  const int i = rem - b * D_INNER;

  float dec[D_STATE], bb[D_STATE], cc[D_STATE], h[D_STATE];
  #pragma unroll
  for (int s = 0; s < D_STATE; s++) {
    float al = A_log[i * D_STATE + s];
    al = fminf(fmaxf(al, -5.0f), 0.0f);
    float a = -__expf(al);
    a = fminf(fmaxf(a, -2.0f), -0.01f);
    dec[s] = a * 0.9f;
    bb[s]  = Bv[i * D_STATE + s] * 0.1f;
    cc[s]  = Cv[i * D_STATE + s];
    h[s]   = 0.0f;
  }

  const size_t base = (size_t)b * SEQ_L * D_INNER + i;
  const int tmain = chunk * SCAN_CL;
  const int tw = (tmain >= SCAN_W) ? (tmain - SCAN_W) : 0;

  // ---- warmup: state updates only (no gate/y/stores) ----
  for (int t0 = tw; t0 < tmain; t0 += 16) {
    float xv[16];
    #pragma unroll
    for (int j = 0; j < 16; j++)
      xv[j] = xssm[base + (size_t)(t0 + j) * D_INNER];
    #pragma unroll
    for (int j = 0; j < 16; j++) {
      const float x = xv[j];
      #pragma unroll
      for (int s = 0; s < D_STATE; s++) {
        h[s] = fmaf(h[s], dec[s], x * bb[s]);
        h[s] = fminf(fmaxf(h[s], -5.0f), 5.0f);
      }
    }
  }

  // ---- main: double-buffered blocks of 8 ----
  float xf[8], gf[8];
  #pragma unroll
  for (int j = 0; j < 8; j++) {
    xf[j] = xssm[base + (size_t)(tmain + j) * D_INNER];
    gf[j] = gate[base + (size_t)(tmain + j) * D_INNER];
  }
  for (int t0 = tmain; t0 < tmain + SCAN_CL; t0 += 8) {
    float xn[8], gn[8];
    if (t0 + 8 < tmain + SCAN_CL) {
      #pragma unroll
      for (int j = 0; j < 8; j++) {
        xn[j] = xssm[base + (size_t)(t0 + 8 + j) * D_INNER];
        gn[j] = gate[base + (size_t)(t0 + 8 + j) * D_INNER];
      }
    }
    #pragma unroll
    for (int j = 0; j < 8; j++) {
      const float x = xf[j];
      float y = 0.0f;
      #pragma unroll
      for (int s = 0; s < D_STATE; s++) {
        h[s] = fmaf(h[s], dec[s], x * bb[s]);
        h[s] = fminf(fmaxf(h[s], -5.0f), 5.0f);
        y = fmaf(h[s], cc[s], y);
      }
      y = fminf(fmaxf(y, -5.0f), 5.0f);
      const float e  = __expf(2.0f * gf[j]);
      const float th = __fdividef(e - 1.0f, e + 1.0f);
      const float p = y * th;
      const u16 h0 = bf_hi(p);
      const u16 h1 = bf_hi(p - bf_f(h0));
      P0[base + (size_t)(t0 + j) * D_INNER] = h0;
      P1[base + (size_t)(t0 + j) * D_INNER] = h1;
    }
    #pragma unroll
    for (int j = 0; j < 8; j++) { xf[j] = xn[j]; gf[j] = gn[j]; }
  }
}

// ---------------------------------------------------------------- launcher
extern "C" void kernel_launch(void* const* d_in, const int* in_sizes, int n_in,
                              void* d_out, int out_size, void* d_ws, size_t ws_size,
                              hipStream_t stream)
{
  const float* x        = (const float*)d_in[0];
  const float* W_in     = (const float*)d_in[1];
  const float* W_out    = (const float*)d_in[2];
  const float* A_log    = (const float*)d_in[3];
  const float* Bmat     = (const float*)d_in[4];
  const float* Cmat     = (const float*)d_in[5];
  const float* ln_in_g  = (const float*)d_in[6];
  const float* ln_in_b  = (const float*)d_in[7];
  const float* ln_out_g = (const float*)d_in[8];
  const float* ln_out_b = (const float*)d_in[9];
  float* out = (float*)d_out;

  // workspace layout (bytes):
  // [xssm 50331648][gate 50331648][xn 33554432][B0,B1,B2 3x6291456][V0,V1 2x3145728]
  // prod P0/P1 (2x25165824) overlays xn+Win region (dead after gemm1);
  // outp (33554432) overlays xssm (dead after scan). Total 159,383,552 B.
  char* ws = (char*)d_ws;
  float* xssm = (float*)(ws);
  float* gate = (float*)(ws + 50331648);
  float* xn   = (float*)(ws + 100663296);
  u16* B0 = (u16*)(ws + 134217728);
  u16* B1 = (u16*)(ws + 140509184);
  u16* B2 = (u16*)(ws + 146800640);
  u16* V0 = (u16*)(ws + 153092096);
  u16* V1 = (u16*)(ws + 156237824);
  u16* P0 = (u16*)xn;
  u16* P1 = P0 + (size_t)MROWS * D_INNER;
  float* outp = xssm;

  // 0) split weights into bf16 terms
  wsplit3_kernel<<<(2 * D_INNER * D_MODEL + 255) / 256, 256, 0, stream>>>(
      W_in, B0, B1, B2, 2 * D_INNER * D_MODEL);
  wsplit2_kernel<<<(D_MODEL * D_INNER + 255) / 256, 256, 0, stream>>>(
      W_out, V0, V1, D_MODEL * D_INNER);

  // 1) LayerNorm-in
  ln_kernel<<<MROWS, 256, 0, stream>>>(x, ln_in_g, ln_in_b, xn);

  // 2) x_proj = clip(xn @ W_in^T) via 6-MFMA 3-term split
  {
    dim3 grid(MROWS / 128, (2 * D_INNER) / 128);   // 64 x 24
    gemm1_kernel<<<grid, 256, 0, stream>>>(xn, B0, B1, B2, xssm, gate);
  }

  // 3) chunked SSM scan -> prod as 2-term bf16 (overlays dead xn/Win)
  scan_kernel<<<(BATCH * D_INNER * SCAN_C) / 256, 256, 0, stream>>>(
      xssm, gate, A_log, Bmat, Cmat, P0, P1);

  // 4) out_pre = clip(prod @ W_out^T) via 3-MFMA 2-term split
  {
    dim3 grid(MROWS / 128, D_MODEL / 128);          // 64 x 8
    gemm2_kernel<<<grid, 256, 0, stream>>>(P0, P1, V0, V1, outp);
  }

  // 5) LayerNorm-out -> d_out
  ln_kernel<<<MROWS, 256, 0, stream>>>(outp, ln_out_g, ln_out_b, out);
}

// Round 4
// 409.070 us; speedup vs baseline: 3.3207x; 1.2125x over previous
//
#include <hip/hip_runtime.h>
#include <cstddef>
#include <cstdint>

#define D_MODEL 1024
#define D_STATE 8
#define D_INNER 1536
#define SEQ_L   2048
#define BATCH   4
#define MROWS   (BATCH * SEQ_L)   // 8192

// chunked scan: 16 chunks of 128, warmup 128 (|decay|<=0.55 -> err ~1e-32)
#define SCAN_CL 128
#define SCAN_W  128
#define SCAN_C  (SEQ_L / SCAN_CL)   // 16

typedef __attribute__((ext_vector_type(8))) short short8;
typedef __attribute__((ext_vector_type(4))) float f32x4;
typedef unsigned int u32;
typedef unsigned short u16;

__device__ __forceinline__ u16 bf_hi(float x) {            // truncate fp32 -> bf16
  return (u16)(__float_as_uint(x) >> 16);
}
__device__ __forceinline__ float bf_f(u16 h) {
  return __uint_as_float(((u32)h) << 16);
}
__device__ __forceinline__ void gload16(const void* g, void* l) {
  __builtin_amdgcn_global_load_lds((const __attribute__((address_space(1))) u32*)g,
                                   (__attribute__((address_space(3))) u32*)l, 16, 0, 0);
}
// LDS bank swizzle: physical 8-elem chunk = logical ^ swz(row). Conflict-free
// fragment reads; global_load_lds coalescing preserved (permute within 64B).
__device__ __forceinline__ int swz4(int row) { return (row ^ (row >> 2)) & 3; }

// ---------------------------------------------------------------- LayerNorm
__global__ __launch_bounds__(256) void ln_kernel(
    const float* __restrict__ x, const float* __restrict__ g,
    const float* __restrict__ b, float* __restrict__ y)
{
  const int row = blockIdx.x;
  const int t = threadIdx.x;
  float4 v = reinterpret_cast<const float4*>(x + (size_t)row * D_MODEL)[t];
  float s  = v.x + v.y + v.z + v.w;
  float s2 = v.x * v.x + v.y * v.y + v.z * v.z + v.w * v.w;
  #pragma unroll
  for (int o = 32; o > 0; o >>= 1) {
    s  += __shfl_down(s, o);
    s2 += __shfl_down(s2, o);
  }
  __shared__ float ls[4], ls2[4];
  const int wid = t >> 6, lid = t & 63;
  if (lid == 0) { ls[wid] = s; ls2[wid] = s2; }
  __syncthreads();
  if (t == 0) {
    ls[0]  = ls[0] + ls[1] + ls[2] + ls[3];
    ls2[0] = ls2[0] + ls2[1] + ls2[2] + ls2[3];
  }
  __syncthreads();
  const float mean = ls[0] * (1.0f / D_MODEL);
  const float var  = ls2[0] * (1.0f / D_MODEL) - mean * mean;
  const float rstd = rsqrtf(var + 1e-5f);
  float4 gv = reinterpret_cast<const float4*>(g)[t];
  float4 bv = reinterpret_cast<const float4*>(b)[t];
  float4 o;
  o.x = (v.x - mean) * rstd * gv.x + bv.x;
  o.y = (v.y - mean) * rstd * gv.y + bv.y;
  o.z = (v.z - mean) * rstd * gv.z + bv.z;
  o.w = (v.w - mean) * rstd * gv.w + bv.w;
  reinterpret_cast<float4*>(y + (size_t)row * D_MODEL)[t] = o;
}

// ------------------------------------------------- weight split kernel
__global__ __launch_bounds__(256) void wsplit2_kernel(
    const float* __restrict__ W, u16* __restrict__ a0, u16* __restrict__ a1, int n)
{
  int i = blockIdx.x * 256 + threadIdx.x;
  if (i >= n) return;
  float x = W[i];
  u16 h0 = bf_hi(x); float r1 = x - bf_f(h0);
  a0[i] = h0; a1[i] = bf_hi(r1);
}

// ---------------------------------------------------------------- GEMM1
// out = clip(xn @ W_in^T). A: fp32 [8192][1024] converted in-kernel to 2-term
// bf16; B: 2-term pre-split bf16 [3072][1024]. 3 MFMAs (a0b0,a0b1,a1b0):
// rep error ~2^-16 — safe: scan is contractive, LN-out amplifies only
// out_pre (GEMM2) errors. 128x128 tile, BK=32, swizzled LDS.
__global__ __launch_bounds__(256, 2) void gemm1_kernel(
    const float* __restrict__ A, const u16* __restrict__ B0,
    const u16* __restrict__ B1,
    float* __restrict__ out0, float* __restrict__ out1)
{
  __shared__ u16 As[2][128 * 32];
  __shared__ u16 Bs[2][128 * 32];
  const int t = threadIdx.x;
  const int wave = t >> 6, lane = t & 63;
  const int wr = wave >> 1, wc = wave & 1;
  const int q = lane >> 4, m16 = lane & 15;
  const int m0 = blockIdx.x * 128, n0 = blockIdx.y * 128;

  // A staging: thread t stages row (t>>1), k-half (t&1)*16 (2 logical chunks)
  const int ar = t >> 1, akh = t & 1;
  const int asw = swz4(ar);
  const float* Ap = A + (size_t)(m0 + ar) * D_MODEL + akh * 16;
  // B staging: lane covers row (lane>>2), physical chunk (lane&3)
  const int lr = lane >> 2;
  const int bch = (lane & 3) ^ swz4(lr);
  const u16* Bsrc[2] = {B0, B1};
  // fragment read offset: (q ^ swz(m16)) * 8
  const int qsw = (q ^ swz4(m16)) * 8;

  f32x4 acc[4][4];
  #pragma unroll
  for (int i = 0; i < 4; i++)
    #pragma unroll
    for (int j = 0; j < 4; j++) acc[i][j] = (f32x4)(0.0f);

  for (int kk = 0; kk < D_MODEL; kk += 32) {
    float4 f[4];
    #pragma unroll
    for (int i = 0; i < 4; i++)
      f[i] = *reinterpret_cast<const float4*>(Ap + kk + i * 4);
    u16 u0[16], u1[16];
    #pragma unroll
    for (int i = 0; i < 4; i++) {
      float ee[4] = {f[i].x, f[i].y, f[i].z, f[i].w};
      #pragma unroll
      for (int j = 0; j < 4; j++) {
        float x = ee[j];
        u16 h0 = bf_hi(x);
        u0[i * 4 + j] = h0;
        u1[i * 4 + j] = bf_hi(x - bf_f(h0));
      }
    }
    __syncthreads();
    // B: async global->LDS, 2 terms x 2 halves per wave, swizzled source chunk
    #pragma unroll
    for (int term = 0; term < 2; term++) {
      #pragma unroll
      for (int j = 0; j < 2; j++) {
        const u16* gp = Bsrc[term] +
            (size_t)(n0 + wave * 32 + j * 16 + lr) * D_MODEL + kk + bch * 8;
        gload16(gp, &Bs[term][(wave * 32 + j * 16) * 32]);
      }
    }
    // A: write converted terms to swizzled physical chunks
    #pragma unroll
    for (int term = 0; term < 2; term++) {
      const u16* uu = term ? u1 : u0;
      #pragma unroll
      for (int c = 0; c < 2; c++) {
        const int pc = (akh * 2 + c) ^ asw;
        short8 s;
        #pragma unroll
        for (int j = 0; j < 8; j++) s[j] = (short)uu[c * 8 + j];
        *reinterpret_cast<short8*>(&As[term][ar * 32 + pc * 8]) = s;
      }
    }
    __syncthreads();
    short8 a0[4], a1[4], b0f[4], b1f[4];
    #pragma unroll
    for (int mt = 0; mt < 4; mt++)
      a0[mt] = *reinterpret_cast<const short8*>(
          &As[0][(wr * 64 + mt * 16 + m16) * 32 + qsw]);
    #pragma unroll
    for (int nt = 0; nt < 4; nt++)
      b0f[nt] = *reinterpret_cast<const short8*>(
          &Bs[0][(wc * 64 + nt * 16 + m16) * 32 + qsw]);
    #pragma unroll
    for (int mt = 0; mt < 4; mt++)
      #pragma unroll
      for (int nt = 0; nt < 4; nt++)
        acc[mt][nt] = __builtin_amdgcn_mfma_f32_16x16x32_bf16(
            a0[mt], b0f[nt], acc[mt][nt], 0, 0, 0);
    #pragma unroll
    for (int nt = 0; nt < 4; nt++)
      b1f[nt] = *reinterpret_cast<const short8*>(
          &Bs[1][(wc * 64 + nt * 16 + m16) * 32 + qsw]);
    #pragma unroll
    for (int mt = 0; mt < 4; mt++)
      #pragma unroll
      for (int nt = 0; nt < 4; nt++)
        acc[mt][nt] = __builtin_amdgcn_mfma_f32_16x16x32_bf16(
            a0[mt], b1f[nt], acc[mt][nt], 0, 0, 0);
    #pragma unroll
    for (int mt = 0; mt < 4; mt++)
      a1[mt] = *reinterpret_cast<const short8*>(
          &As[1][(wr * 64 + mt * 16 + m16) * 32 + qsw]);
    #pragma unroll
    for (int mt = 0; mt < 4; mt++)
      #pragma unroll
      for (int nt = 0; nt < 4; nt++)
        acc[mt][nt] = __builtin_amdgcn_mfma_f32_16x16x32_bf16(
            a1[mt], b0f[nt], acc[mt][nt], 0, 0, 0);
  }
  // epilogue: C/D layout col=lane&15, row=(lane>>4)*4+reg
  #pragma unroll
  for (int mt = 0; mt < 4; mt++) {
    #pragma unroll
    for (int nt = 0; nt < 4; nt++) {
      const int col = n0 + wc * 64 + nt * 16 + m16;
      #pragma unroll
      for (int r = 0; r < 4; r++) {
        const int row = m0 + wr * 64 + mt * 16 + q * 4 + r;
        float v = fminf(fmaxf(acc[mt][nt][r], -5.0f), 5.0f);
        if (col < D_INNER) out0[(size_t)row * D_INNER + col] = v;
        else               out1[(size_t)row * D_INNER + (col - D_INNER)] = v;
      }
    }
  }
}

// ---------------------------------------------------------------- GEMM2
// out = clip(prod @ W_out^T). A: 2-term bf16 [8192][1536]; B: 2-term
// [1024][1536]. 3 MFMAs. All staging via global_load_lds, swizzled.
__global__ __launch_bounds__(256, 2) void gemm2_kernel(
    const u16* __restrict__ P0, const u16* __restrict__ P1,
    const u16* __restrict__ V0, const u16* __restrict__ V1,
    float* __restrict__ out)
{
  __shared__ u16 As[2][128 * 32];
  __shared__ u16 Bs[2][128 * 32];
  const int t = threadIdx.x;
  const int wave = t >> 6, lane = t & 63;
  const int wr = wave >> 1, wc = wave & 1;
  const int q = lane >> 4, m16 = lane & 15;
  const int m0 = blockIdx.x * 128, n0 = blockIdx.y * 128;
  const int lr = lane >> 2;
  const int sch = (lane & 3) ^ swz4(lr);
  const int qsw = (q ^ swz4(m16)) * 8;
  const u16* Asrc[2] = {P0, P1};
  const u16* Bsrc[2] = {V0, V1};

  f32x4 acc[4][4];
  #pragma unroll
  for (int i = 0; i < 4; i++)
    #pragma unroll
    for (int j = 0; j < 4; j++) acc[i][j] = (f32x4)(0.0f);

  for (int kk = 0; kk < D_INNER; kk += 32) {
    __syncthreads();
    #pragma unroll
    for (int term = 0; term < 2; term++) {
      #pragma unroll
      for (int j = 0; j < 2; j++) {
        const u16* ga = Asrc[term] +
            (size_t)(m0 + wave * 32 + j * 16 + lr) * D_INNER + kk + sch * 8;
        gload16(ga, &As[term][(wave * 32 + j * 16) * 32]);
        const u16* gb = Bsrc[term] +
            (size_t)(n0 + wave * 32 + j * 16 + lr) * D_INNER + kk + sch * 8;
        gload16(gb, &Bs[term][(wave * 32 + j * 16) * 32]);
      }
    }
    __syncthreads();
    short8 a0[4], a1[4], b0f[4], b1f[4];
    #pragma unroll
    for (int mt = 0; mt < 4; mt++)
      a0[mt] = *reinterpret_cast<const short8*>(
          &As[0][(wr * 64 + mt * 16 + m16) * 32 + qsw]);
    #pragma unroll
    for (int nt = 0; nt < 4; nt++)
      b0f[nt] = *reinterpret_cast<const short8*>(
          &Bs[0][(wc * 64 + nt * 16 + m16) * 32 + qsw]);
    #pragma unroll
    for (int mt = 0; mt < 4; mt++)
      #pragma unroll
      for (int nt = 0; nt < 4; nt++)
        acc[mt][nt] = __builtin_amdgcn_mfma_f32_16x16x32_bf16(
            a0[mt], b0f[nt], acc[mt][nt], 0, 0, 0);
    #pragma unroll
    for (int nt = 0; nt < 4; nt++)
      b1f[nt] = *reinterpret_cast<const short8*>(
          &Bs[1][(wc * 64 + nt * 16 + m16) * 32 + qsw]);
    #pragma unroll
    for (int mt = 0; mt < 4; mt++)
      #pragma unroll
      for (int nt = 0; nt < 4; nt++)
        acc[mt][nt] = __builtin_amdgcn_mfma_f32_16x16x32_bf16(
            a0[mt], b1f[nt], acc[mt][nt], 0, 0, 0);
    #pragma unroll
    for (int mt = 0; mt < 4; mt++)
      a1[mt] = *reinterpret_cast<const short8*>(
          &As[1][(wr * 64 + mt * 16 + m16) * 32 + qsw]);
    #pragma unroll
    for (int mt = 0; mt < 4; mt++)
      #pragma unroll
      for (int nt = 0; nt < 4; nt++)
        acc[mt][nt] = __builtin_amdgcn_mfma_f32_16x16x32_bf16(
            a1[mt], b0f[nt], acc[mt][nt], 0, 0, 0);
  }
  #pragma unroll
  for (int mt = 0; mt < 4; mt++) {
    #pragma unroll
    for (int nt = 0; nt < 4; nt++) {
      const int col = n0 + wc * 64 + nt * 16 + m16;
      #pragma unroll
      for (int r = 0; r < 4; r++) {
        const int row = m0 + wr * 64 + mt * 16 + q * 4 + r;
        float v = fminf(fmaxf(acc[mt][nt][r], -5.0f), 5.0f);
        out[(size_t)row * D_MODEL + col] = v;
      }
    }
  }
}

// --------------------------------------------------------------- SSM scan
// Chunked: one thread per (chunk, b, i); warmup from h=0 (contraction).
__global__ __launch_bounds__(256) void scan_kernel(
    const float* __restrict__ xssm, const float* __restrict__ gate,
    const float* __restrict__ A_log, const float* __restrict__ Bv,
    const float* __restrict__ Cv, u16* __restrict__ P0, u16* __restrict__ P1)
{
  const int gid = blockIdx.x * 256 + threadIdx.x;       // 0 .. 98303
  const int chunk = gid / (BATCH * D_INNER);            // 0..15
  const int rem = gid - chunk * (BATCH * D_INNER);
  const int b = rem / D_INNER;
  const int i = rem - b * D_INNER;

  float dec[D_STATE], bb[D_STATE], cc[D_STATE], h[D_STATE];
  #pragma unroll
  for (int s = 0; s < D_STATE; s++) {
    float al = A_log[i * D_STATE + s];
    al = fminf(fmaxf(al, -5.0f), 0.0f);
    float a = -__expf(al);
    a = fminf(fmaxf(a, -2.0f), -0.01f);
    dec[s] = a * 0.9f;
    bb[s]  = Bv[i * D_STATE + s] * 0.1f;
    cc[s]  = Cv[i * D_STATE + s];
    h[s]   = 0.0f;
  }

  const size_t base = (size_t)b * SEQ_L * D_INNER + i;
  const int tmain = chunk * SCAN_CL;
  const int tw = (tmain >= SCAN_W) ? (tmain - SCAN_W) : 0;

  for (int t0 = tw; t0 < tmain; t0 += 16) {
    float xv[16];
    #pragma unroll
    for (int j = 0; j < 16; j++)
      xv[j] = xssm[base + (size_t)(t0 + j) * D_INNER];
    #pragma unroll
    for (int j = 0; j < 16; j++) {
      const float x = xv[j];
      #pragma unroll
      for (int s = 0; s < D_STATE; s++) {
        h[s] = fmaf(h[s], dec[s], x * bb[s]);
        h[s] = fminf(fmaxf(h[s], -5.0f), 5.0f);
      }
    }
  }

  float xf[8], gf[8];
  #pragma unroll
  for (int j = 0; j < 8; j++) {
    xf[j] = xssm[base + (size_t)(tmain + j) * D_INNER];
    gf[j] = gate[base + (size_t)(tmain + j) * D_INNER];
  }
  for (int t0 = tmain; t0 < tmain + SCAN_CL; t0 += 8) {
    float xn[8], gn[8];
    if (t0 + 8 < tmain + SCAN_CL) {
      #pragma unroll
      for (int j = 0; j < 8; j++) {
        xn[j] = xssm[base + (size_t)(t0 + 8 + j) * D_INNER];
        gn[j] = gate[base + (size_t)(t0 + 8 + j) * D_INNER];
      }
    }
    #pragma unroll
    for (int j = 0; j < 8; j++) {
      const float x = xf[j];
      float y = 0.0f;
      #pragma unroll
      for (int s = 0; s < D_STATE; s++) {
        h[s] = fmaf(h[s], dec[s], x * bb[s]);
        h[s] = fminf(fmaxf(h[s], -5.0f), 5.0f);
        y = fmaf(h[s], cc[s], y);
      }
      y = fminf(fmaxf(y, -5.0f), 5.0f);
      const float e  = __expf(2.0f * gf[j]);
      const float th = __fdividef(e - 1.0f, e + 1.0f);
      const float p = y * th;
      const u16 h0 = bf_hi(p);
      const u16 h1 = bf_hi(p - bf_f(h0));
      P0[base + (size_t)(t0 + j) * D_INNER] = h0;
      P1[base + (size_t)(t0 + j) * D_INNER] = h1;
    }
    #pragma unroll
    for (int j = 0; j < 8; j++) { xf[j] = xn[j]; gf[j] = gn[j]; }
  }
}

// ---------------------------------------------------------------- launcher
extern "C" void kernel_launch(void* const* d_in, const int* in_sizes, int n_in,
                              void* d_out, int out_size, void* d_ws, size_t ws_size,
                              hipStream_t stream)
{
  const float* x        = (const float*)d_in[0];
  const float* W_in     = (const float*)d_in[1];
  const float* W_out    = (const float*)d_in[2];
  const float* A_log    = (const float*)d_in[3];
  const float* Bmat     = (const float*)d_in[4];
  const float* Cmat     = (const float*)d_in[5];
  const float* ln_in_g  = (const float*)d_in[6];
  const float* ln_in_b  = (const float*)d_in[7];
  const float* ln_out_g = (const float*)d_in[8];
  const float* ln_out_b = (const float*)d_in[9];
  float* out = (float*)d_out;

  char* ws = (char*)d_ws;
  float* xssm = (float*)(ws);
  float* gate = (float*)(ws + 50331648);
  float* xn   = (float*)(ws + 100663296);
  u16* B0 = (u16*)(ws + 134217728);
  u16* B1 = (u16*)(ws + 140509184);
  u16* V0 = (u16*)(ws + 153092096);
  u16* V1 = (u16*)(ws + 156237824);
  u16* P0 = (u16*)xn;                               // overlays dead xn
  u16* P1 = P0 + (size_t)MROWS * D_INNER;
  float* outp = xssm;                               // overlays dead xssm

  // 0) split weights into 2-term bf16
  wsplit2_kernel<<<(2 * D_INNER * D_MODEL + 255) / 256, 256, 0, stream>>>(
      W_in, B0, B1, 2 * D_INNER * D_MODEL);
  wsplit2_kernel<<<(D_MODEL * D_INNER + 255) / 256, 256, 0, stream>>>(
      W_out, V0, V1, D_MODEL * D_INNER);

  // 1) LayerNorm-in
  ln_kernel<<<MROWS, 256, 0, stream>>>(x, ln_in_g, ln_in_b, xn);

  // 2) x_proj = clip(xn @ W_in^T) via 3-MFMA 2-term split
  {
    dim3 grid(MROWS / 128, (2 * D_INNER) / 128);   // 64 x 24
    gemm1_kernel<<<grid, 256, 0, stream>>>(xn, B0, B1, xssm, gate);
  }

  // 3) chunked SSM scan -> prod as 2-term bf16
  scan_kernel<<<(BATCH * D_INNER * SCAN_C) / 256, 256, 0, stream>>>(
      xssm, gate, A_log, Bmat, Cmat, P0, P1);

  // 4) out_pre = clip(prod @ W_out^T) via 3-MFMA 2-term split
  {
    dim3 grid(MROWS / 128, D_MODEL / 128);          // 64 x 8
    gemm2_kernel<<<grid, 256, 0, stream>>>(P0, P1, V0, V1, outp);
  }

  // 5) LayerNorm-out -> d_out
  ln_kernel<<<MROWS, 256, 0, stream>>>(outp, ln_out_g, ln_out_b, out);
}

// Round 5
// 385.671 us; speedup vs baseline: 3.5222x; 1.0607x over previous
//
#include <hip/hip_runtime.h>
#include <cstddef>
#include <cstdint>

#define D_MODEL 1024
#define D_STATE 8
#define D_INNER 1536
#define SEQ_L   2048
#define BATCH   4
#define MROWS   (BATCH * SEQ_L)   // 8192

// chunked scan: 16 chunks of 128, warmup 128 (|decay|<=0.55 -> err ~1e-32)
#define SCAN_CL 128
#define SCAN_W  128
#define SCAN_C  (SEQ_L / SCAN_CL)   // 16

typedef __attribute__((ext_vector_type(8))) short short8;
typedef __attribute__((ext_vector_type(4))) float f32x4;
typedef unsigned int u32;
typedef unsigned short u16;

__device__ __forceinline__ u16 bf_hi(float x) {            // truncate fp32 -> bf16
  return (u16)(__float_as_uint(x) >> 16);
}
__device__ __forceinline__ float bf_f(u16 h) {
  return __uint_as_float(((u32)h) << 16);
}
__device__ __forceinline__ void gload16(const void* g, void* l) {
  __builtin_amdgcn_global_load_lds((const __attribute__((address_space(1))) u32*)g,
                                   (__attribute__((address_space(3))) u32*)l, 16, 0, 0);
}
// LDS bank swizzle: physical 8-elem chunk = logical ^ swz4(row).
__device__ __forceinline__ int swz4(int row) { return (row ^ (row >> 2)) & 3; }

// ---------------------------------------------------------------- LayerNorm
// Plain fp32-out variant (used for LN-out -> d_out).
__global__ __launch_bounds__(256) void ln_kernel(
    const float* __restrict__ x, const float* __restrict__ g,
    const float* __restrict__ b, float* __restrict__ y)
{
  const int row = blockIdx.x;
  const int t = threadIdx.x;
  float4 v = reinterpret_cast<const float4*>(x + (size_t)row * D_MODEL)[t];
  float s  = v.x + v.y + v.z + v.w;
  float s2 = v.x * v.x + v.y * v.y + v.z * v.z + v.w * v.w;
  #pragma unroll
  for (int o = 32; o > 0; o >>= 1) {
    s  += __shfl_down(s, o);
    s2 += __shfl_down(s2, o);
  }
  __shared__ float ls[4], ls2[4];
  const int wid = t >> 6, lid = t & 63;
  if (lid == 0) { ls[wid] = s; ls2[wid] = s2; }
  __syncthreads();
  if (t == 0) {
    ls[0]  = ls[0] + ls[1] + ls[2] + ls[3];
    ls2[0] = ls2[0] + ls2[1] + ls2[2] + ls2[3];
  }
  __syncthreads();
  const float mean = ls[0] * (1.0f / D_MODEL);
  const float var  = ls2[0] * (1.0f / D_MODEL) - mean * mean;
  const float rstd = rsqrtf(var + 1e-5f);
  float4 gv = reinterpret_cast<const float4*>(g)[t];
  float4 bv = reinterpret_cast<const float4*>(b)[t];
  float4 o;
  o.x = (v.x - mean) * rstd * gv.x + bv.x;
  o.y = (v.y - mean) * rstd * gv.y + bv.y;
  o.z = (v.z - mean) * rstd * gv.z + bv.z;
  o.w = (v.w - mean) * rstd * gv.w + bv.w;
  reinterpret_cast<float4*>(y + (size_t)row * D_MODEL)[t] = o;
}

// LN-in variant: writes 2-term bf16 split planes (feeds GEMM1 directly).
__global__ __launch_bounds__(256) void ln_split_kernel(
    const float* __restrict__ x, const float* __restrict__ g,
    const float* __restrict__ b, u16* __restrict__ y0, u16* __restrict__ y1)
{
  const int row = blockIdx.x;
  const int t = threadIdx.x;
  float4 v = reinterpret_cast<const float4*>(x + (size_t)row * D_MODEL)[t];
  float s  = v.x + v.y + v.z + v.w;
  float s2 = v.x * v.x + v.y * v.y + v.z * v.z + v.w * v.w;
  #pragma unroll
  for (int o = 32; o > 0; o >>= 1) {
    s  += __shfl_down(s, o);
    s2 += __shfl_down(s2, o);
  }
  __shared__ float ls[4], ls2[4];
  const int wid = t >> 6, lid = t & 63;
  if (lid == 0) { ls[wid] = s; ls2[wid] = s2; }
  __syncthreads();
  if (t == 0) {
    ls[0]  = ls[0] + ls[1] + ls[2] + ls[3];
    ls2[0] = ls2[0] + ls2[1] + ls2[2] + ls2[3];
  }
  __syncthreads();
  const float mean = ls[0] * (1.0f / D_MODEL);
  const float var  = ls2[0] * (1.0f / D_MODEL) - mean * mean;
  const float rstd = rsqrtf(var + 1e-5f);
  float4 gv = reinterpret_cast<const float4*>(g)[t];
  float4 bv = reinterpret_cast<const float4*>(b)[t];
  float o[4];
  o[0] = (v.x - mean) * rstd * gv.x + bv.x;
  o[1] = (v.y - mean) * rstd * gv.y + bv.y;
  o[2] = (v.z - mean) * rstd * gv.z + bv.z;
  o[3] = (v.w - mean) * rstd * gv.w + bv.w;
  ushort4 h0, h1;
  u16 a, c;
  a = bf_hi(o[0]); c = bf_hi(o[0] - bf_f(a)); h0.x = a; h1.x = c;
  a = bf_hi(o[1]); c = bf_hi(o[1] - bf_f(a)); h0.y = a; h1.y = c;
  a = bf_hi(o[2]); c = bf_hi(o[2] - bf_f(a)); h0.z = a; h1.z = c;
  a = bf_hi(o[3]); c = bf_hi(o[3] - bf_f(a)); h0.w = a; h1.w = c;
  reinterpret_cast<ushort4*>(y0 + (size_t)row * D_MODEL)[t] = h0;
  reinterpret_cast<ushort4*>(y1 + (size_t)row * D_MODEL)[t] = h1;
}

// ------------------------------------------------- weight split kernel
__global__ __launch_bounds__(256) void wsplit2_kernel(
    const float* __restrict__ W, u16* __restrict__ a0, u16* __restrict__ a1, int n)
{
  int i = blockIdx.x * 256 + threadIdx.x;
  if (i >= n) return;
  float x = W[i];
  u16 h0 = bf_hi(x); float r1 = x - bf_f(h0);
  a0[i] = h0; a1[i] = bf_hi(r1);
}

// ---------------------------------------------------------------- GEMM
// out = clip(A @ B^T) with A,B given as 2-term bf16 splits (3 MFMA combos:
// a0b0 + a0b1 + a1b0; rep error ~2^-16). Pure m97 K-loop: all staging via
// global_load_lds (8/wave/iter), swizzled LDS chunks, 16 ds_read_b128,
// 48 MFMA, 2 barriers. 128x128 tile, BK=32, 3 blocks/CU.
// Epilogue split: col<split -> out0[r*ld0+col] else out1[r*ld1+(col-split)].
__global__ __launch_bounds__(256, 3) void gemm_kernel(
    const u16* __restrict__ A0, const u16* __restrict__ A1,
    const u16* __restrict__ B0, const u16* __restrict__ B1,
    float* __restrict__ out0, float* __restrict__ out1,
    int K, int split, int ld0, int ld1)
{
  __shared__ u16 As[2][128 * 32];
  __shared__ u16 Bs[2][128 * 32];
  const int t = threadIdx.x;
  const int wave = t >> 6, lane = t & 63;
  const int wr = wave >> 1, wc = wave & 1;
  const int q = lane >> 4, m16 = lane & 15;
  const int m0 = blockIdx.x * 128, n0 = blockIdx.y * 128;
  const int lr = lane >> 2;                    // row within 16-row group
  const int sch = (lane & 3) ^ swz4(lr);       // swizzled source chunk
  const int qsw = (q ^ swz4(m16)) * 8;         // swizzled fragment offset
  const u16* Asrc[2] = {A0, A1};
  const u16* Bsrc[2] = {B0, B1};

  f32x4 acc[4][4];
  #pragma unroll
  for (int i = 0; i < 4; i++)
    #pragma unroll
    for (int j = 0; j < 4; j++) acc[i][j] = (f32x4)(0.0f);

  for (int kk = 0; kk < K; kk += 32) {
    __syncthreads();
    #pragma unroll
    for (int term = 0; term < 2; term++) {
      #pragma unroll
      for (int j = 0; j < 2; j++) {
        const u16* ga = Asrc[term] +
            (size_t)(m0 + wave * 32 + j * 16 + lr) * K + kk + sch * 8;
        gload16(ga, &As[term][(wave * 32 + j * 16) * 32]);
        const u16* gb = Bsrc[term] +
            (size_t)(n0 + wave * 32 + j * 16 + lr) * K + kk + sch * 8;
        gload16(gb, &Bs[term][(wave * 32 + j * 16) * 32]);
      }
    }
    __syncthreads();
    short8 a0[4], a1[4], b0f[4], b1f[4];
    #pragma unroll
    for (int mt = 0; mt < 4; mt++)
      a0[mt] = *reinterpret_cast<const short8*>(
          &As[0][(wr * 64 + mt * 16 + m16) * 32 + qsw]);
    #pragma unroll
    for (int nt = 0; nt < 4; nt++)
      b0f[nt] = *reinterpret_cast<const short8*>(
          &Bs[0][(wc * 64 + nt * 16 + m16) * 32 + qsw]);
    #pragma unroll
    for (int mt = 0; mt < 4; mt++)
      #pragma unroll
      for (int nt = 0; nt < 4; nt++)
        acc[mt][nt] = __builtin_amdgcn_mfma_f32_16x16x32_bf16(
            a0[mt], b0f[nt], acc[mt][nt], 0, 0, 0);
    #pragma unroll
    for (int nt = 0; nt < 4; nt++)
      b1f[nt] = *reinterpret_cast<const short8*>(
          &Bs[1][(wc * 64 + nt * 16 + m16) * 32 + qsw]);
    #pragma unroll
    for (int mt = 0; mt < 4; mt++)
      #pragma unroll
      for (int nt = 0; nt < 4; nt++)
        acc[mt][nt] = __builtin_amdgcn_mfma_f32_16x16x32_bf16(
            a0[mt], b1f[nt], acc[mt][nt], 0, 0, 0);
    #pragma unroll
    for (int mt = 0; mt < 4; mt++)
      a1[mt] = *reinterpret_cast<const short8*>(
          &As[1][(wr * 64 + mt * 16 + m16) * 32 + qsw]);
    #pragma unroll
    for (int mt = 0; mt < 4; mt++)
      #pragma unroll
      for (int nt = 0; nt < 4; nt++)
        acc[mt][nt] = __builtin_amdgcn_mfma_f32_16x16x32_bf16(
            a1[mt], b0f[nt], acc[mt][nt], 0, 0, 0);
  }
  // epilogue: C/D layout col=lane&15, row=(lane>>4)*4+reg
  #pragma unroll
  for (int mt = 0; mt < 4; mt++) {
    #pragma unroll
    for (int nt = 0; nt < 4; nt++) {
      const int col = n0 + wc * 64 + nt * 16 + m16;
      #pragma unroll
      for (int r = 0; r < 4; r++) {
        const int row = m0 + wr * 64 + mt * 16 + q * 4 + r;
        float v = fminf(fmaxf(acc[mt][nt][r], -5.0f), 5.0f);
        if (col < split) out0[(size_t)row * ld0 + col] = v;
        else             out1[(size_t)row * ld1 + (col - split)] = v;
      }
    }
  }
}

// --------------------------------------------------------------- SSM scan
// Chunked: one thread per (chunk, b, i); warmup from h=0 (contraction,
// |decay| <= ~0.55 -> warmup error ~1e-32). Chunk 0 exact.
__global__ __launch_bounds__(256) void scan_kernel(
    const float* __restrict__ xssm, const float* __restrict__ gate,
    const float* __restrict__ A_log, const float* __restrict__ Bv,
    const float* __restrict__ Cv, u16* __restrict__ P0, u16* __restrict__ P1)
{
  const int gid = blockIdx.x * 256 + threadIdx.x;       // 0 .. 98303
  const int chunk = gid / (BATCH * D_INNER);            // 0..15
  const int rem = gid - chunk * (BATCH * D_INNER);
  const int b = rem / D_INNER;
  const int i = rem - b * D_INNER;

  float dec[D_STATE], bb[D_STATE], cc[D_STATE], h[D_STATE];
  #pragma unroll
  for (int s = 0; s < D_STATE; s++) {
    float al = A_log[i * D_STATE + s];
    al = fminf(fmaxf(al, -5.0f), 0.0f);
    float a = -__expf(al);
    a = fminf(fmaxf(a, -2.0f), -0.01f);
    dec[s] = a * 0.9f;
    bb[s]  = Bv[i * D_STATE + s] * 0.1f;
    cc[s]  = Cv[i * D_STATE + s];
    h[s]   = 0.0f;
  }

  const size_t base = (size_t)b * SEQ_L * D_INNER + i;
  const int tmain = chunk * SCAN_CL;
  const int tw = (tmain >= SCAN_W) ? (tmain - SCAN_W) : 0;

  for (int t0 = tw; t0 < tmain; t0 += 16) {
    float xv[16];
    #pragma unroll
    for (int j = 0; j < 16; j++)
      xv[j] = xssm[base + (size_t)(t0 + j) * D_INNER];
    #pragma unroll
    for (int j = 0; j < 16; j++) {
      const float x = xv[j];
      #pragma unroll
      for (int s = 0; s < D_STATE; s++) {
        h[s] = fmaf(h[s], dec[s], x * bb[s]);
        h[s] = fminf(fmaxf(h[s], -5.0f), 5.0f);
      }
    }
  }

  float xf[8], gf[8];
  #pragma unroll
  for (int j = 0; j < 8; j++) {
    xf[j] = xssm[base + (size_t)(tmain + j) * D_INNER];
    gf[j] = gate[base + (size_t)(tmain + j) * D_INNER];
  }
  for (int t0 = tmain; t0 < tmain + SCAN_CL; t0 += 8) {
    float xn[8], gn[8];
    if (t0 + 8 < tmain + SCAN_CL) {
      #pragma unroll
      for (int j = 0; j < 8; j++) {
        xn[j] = xssm[base + (size_t)(t0 + 8 + j) * D_INNER];
        gn[j] = gate[base + (size_t)(t0 + 8 + j) * D_INNER];
      }
    }
    #pragma unroll
    for (int j = 0; j < 8; j++) {
      const float x = xf[j];
      float y = 0.0f;
      #pragma unroll
      for (int s = 0; s < D_STATE; s++) {
        h[s] = fmaf(h[s], dec[s], x * bb[s]);
        h[s] = fminf(fmaxf(h[s], -5.0f), 5.0f);
        y = fmaf(h[s], cc[s], y);
      }
      y = fminf(fmaxf(y, -5.0f), 5.0f);
      const float e  = __expf(2.0f * gf[j]);
      const float th = __fdividef(e - 1.0f, e + 1.0f);
      const float p = y * th;
      const u16 h0 = bf_hi(p);
      const u16 h1 = bf_hi(p - bf_f(h0));
      P0[base + (size_t)(t0 + j) * D_INNER] = h0;
      P1[base + (size_t)(t0 + j) * D_INNER] = h1;
    }
    #pragma unroll
    for (int j = 0; j < 8; j++) { xf[j] = xn[j]; gf[j] = gn[j]; }
  }
}

// ---------------------------------------------------------------- launcher
extern "C" void kernel_launch(void* const* d_in, const int* in_sizes, int n_in,
                              void* d_out, int out_size, void* d_ws, size_t ws_size,
                              hipStream_t stream)
{
  const float* x        = (const float*)d_in[0];
  const float* W_in     = (const float*)d_in[1];
  const float* W_out    = (const float*)d_in[2];
  const float* A_log    = (const float*)d_in[3];
  const float* Bmat     = (const float*)d_in[4];
  const float* Cmat     = (const float*)d_in[5];
  const float* ln_in_g  = (const float*)d_in[6];
  const float* ln_in_b  = (const float*)d_in[7];
  const float* ln_out_g = (const float*)d_in[8];
  const float* ln_out_b = (const float*)d_in[9];
  float* out = (float*)d_out;

  // workspace (bytes):
  // [xssm 50331648][gate 50331648][xn0 16777216][xn1 16777216][B0 6291456]
  // [B1 6291456][gap][V0 3145728][V1 3145728]  total 159,383,552
  // P0/P1 (2x25165824) overlay xn0/xn1/B0/B1 (dead after gemm1);
  // outp overlays xssm (dead after scan).
  char* ws = (char*)d_ws;
  float* xssm = (float*)(ws);
  float* gate = (float*)(ws + 50331648);
  u16* xn0 = (u16*)(ws + 100663296);
  u16* xn1 = (u16*)(ws + 117440512);
  u16* B0  = (u16*)(ws + 134217728);
  u16* B1  = (u16*)(ws + 140509184);
  u16* V0  = (u16*)(ws + 153092096);
  u16* V1  = (u16*)(ws + 156237824);
  u16* P0  = (u16*)(ws + 100663296);
  u16* P1  = P0 + (size_t)MROWS * D_INNER;
  float* outp = xssm;

  // 0) split weights into 2-term bf16
  wsplit2_kernel<<<(2 * D_INNER * D_MODEL + 255) / 256, 256, 0, stream>>>(
      W_in, B0, B1, 2 * D_INNER * D_MODEL);
  wsplit2_kernel<<<(D_MODEL * D_INNER + 255) / 256, 256, 0, stream>>>(
      W_out, V0, V1, D_MODEL * D_INNER);

  // 1) LayerNorm-in -> 2-term bf16 planes
  ln_split_kernel<<<MROWS, 256, 0, stream>>>(x, ln_in_g, ln_in_b, xn0, xn1);

  // 2) x_proj = clip(xn @ W_in^T), split-store xssm/gate
  {
    dim3 grid(MROWS / 128, (2 * D_INNER) / 128);   // 64 x 24
    gemm_kernel<<<grid, 256, 0, stream>>>(xn0, xn1, B0, B1, xssm, gate,
                                          D_MODEL, D_INNER, D_INNER, D_INNER);
  }

  // 3) chunked SSM scan -> prod as 2-term bf16
  scan_kernel<<<(BATCH * D_INNER * SCAN_C) / 256, 256, 0, stream>>>(
      xssm, gate, A_log, Bmat, Cmat, P0, P1);

  // 4) out_pre = clip(prod @ W_out^T)
  {
    dim3 grid(MROWS / 128, D_MODEL / 128);          // 64 x 8
    gemm_kernel<<<grid, 256, 0, stream>>>(P0, P1, V0, V1, outp, outp,
                                          D_INNER, D_MODEL, D_MODEL, D_MODEL);
  }

  // 5) LayerNorm-out -> d_out
  ln_kernel<<<MROWS, 256, 0, stream>>>(outp, ln_out_g, ln_out_b, out);
}